// Round 4
// baseline (329.401 us; speedup 1.0000x reference)
//
#include <hip/hip_runtime.h>

typedef __attribute__((ext_vector_type(8))) short short8;
typedef __attribute__((ext_vector_type(4))) float f32x4;
typedef __attribute__((ext_vector_type(2))) float f32x2;

#define NBMAX 512
#define CAP 8192   // per-bucket stage capacity; mean load 4096, sigma ~64

__device__ inline unsigned short f2bf(float f) {
  union { float f; unsigned u; } v; v.f = f;
  unsigned r = v.u + 0x7fffu + ((v.u >> 16) & 1u);
  return (unsigned short)(r >> 16);
}

// packed accumulate: uint4 of 8 bf16 -> 4x f32x2 (v_pk_add_f32)
__device__ inline void addf2(f32x2 (&a)[4], uint4 v) {
  union { uint2 u; f32x2 f; } t;
  t.u.x = v.x << 16; t.u.y = v.x & 0xffff0000u; a[0] += t.f;
  t.u.x = v.y << 16; t.u.y = v.y & 0xffff0000u; a[1] += t.f;
  t.u.x = v.z << 16; t.u.y = v.z & 0xffff0000u; a[2] += t.f;
  t.u.x = v.w << 16; t.u.y = v.w & 0xffff0000u; a[3] += t.f;
}

__device__ inline int load_src(const int* ei, int E, int e, int f64) {
  return f64 ? ei[2 * e] : ei[e];
}
__device__ inline int load_dst(const int* ei, int E, int e, int f64) {
  return f64 ? ei[2 * (E + e)] : ei[E + e];
}

// ---------------- prep: scatter (CSR phase A) + x->bf16 cast + W permute ----------------
// One launch, three block ranges:
//   [0, SB)        : edge scatter into bucket stage (dst>>8 buckets)
//   [SB, SB+4)     : one-time W cast+permute into MFMA B-fragment order
//   [SB+4, ...)    : x (f32) -> xb (bf16) streaming cast
__global__ __launch_bounds__(256) void prep(
    const int* __restrict__ ei, int E,
    int* __restrict__ btot, int2* __restrict__ stage, int SB,
    const float* __restrict__ x, unsigned short* __restrict__ xb, int n8,
    const float* __restrict__ W1l, const float* __restrict__ W1r,
    const float* __restrict__ W2l, const float* __restrict__ W2r,
    unsigned short* __restrict__ Wp) {
  __shared__ int lcnt[NBMAX];
  __shared__ int lbase[NBMAX];
  __shared__ int sflag;
  const int b = blockIdx.x;
  const int t = threadIdx.x;

  if (b < SB) {
    // ---- scatter ----
    if (t == 0) sflag = 0;
    for (int i = t; i < NBMAX; i += 256) lcnt[i] = 0;
    __syncthreads();
    const int e0 = b * 4096;
    {
      int e = e0 + t;
      int v = (e < E) ? ei[2 * e + 1] : 0;   // in-bounds under both layouts
      if (v) atomicOr(&sflag, 1);
    }
    __syncthreads();
    const int f64 = (sflag == 0) ? 1 : 0;

    int srcs[16], bks[16];
    int dsts[16];
#pragma unroll
    for (int i = 0; i < 16; ++i) {
      int e = e0 + i * 256 + t;
      if (e < E) {
        srcs[i] = load_src(ei, E, e, f64);
        int d = load_dst(ei, E, e, f64);
        dsts[i] = d;
        bks[i] = d >> 8;
        atomicAdd(&lcnt[d >> 8], 1);
      } else {
        bks[i] = -1;
      }
    }
    __syncthreads();
    for (int i = t; i < NBMAX; i += 256) {
      int c = lcnt[i];
      lbase[i] = c ? atomicAdd(&btot[i], c) : 0;
    }
    __syncthreads();
    for (int i = t; i < NBMAX; i += 256) lcnt[i] = 0;
    __syncthreads();
#pragma unroll
    for (int i = 0; i < 16; ++i) {
      int bk = bks[i];
      if (bk >= 0) {
        int r = atomicAdd(&lcnt[bk], 1);
        stage[(size_t)bk * CAP + lbase[bk] + r] = make_int2(srcs[i], dsts[i]);
      }
    }
    return;
  }

  if (b < SB + 4) {
    // ---- W cast + permute (grid-invariant, done once) ----
    const int m = b - SB;
    const float* W = (m == 0) ? W1l : (m == 1) ? W1r : (m == 2) ? W2l : W2r;
    unsigned short* dst = Wp + (size_t)m * 16384;
#pragma unroll
    for (int it = 0; it < 8; ++it) {
      int id = it * 256 + t;
      int j = id >> 4;
      int kc = id & 15;
      int s = kc >> 2, q = kc & 3;
      int jt = j >> 4, nn2 = j & 15;
      int c = (s * 8 + jt) * 4 + q;
      const float* src = W + j * 128 + kc * 8;
      union { unsigned short u[8]; uint4 v; } tv;
#pragma unroll
      for (int k = 0; k < 8; ++k) tv.u[k] = f2bf(src[k]);
      *(uint4*)(dst + (c * 16 + nn2) * 8) = tv.v;
    }
    return;
  }

  // ---- x -> bf16 cast ----
  const int cb = b - SB - 4;
  const int nxb = gridDim.x - SB - 4;
  int i = cb * 256 + t;
  const int stride = nxb * 256;
  for (; i < n8; i += stride) {
    float4 v0 = ((const float4*)x)[2 * i];
    float4 v1 = ((const float4*)x)[2 * i + 1];
    union { unsigned short u[8]; uint4 v; } tv;
    tv.u[0] = f2bf(v0.x); tv.u[1] = f2bf(v0.y);
    tv.u[2] = f2bf(v0.z); tv.u[3] = f2bf(v0.w);
    tv.u[4] = f2bf(v1.x); tv.u[5] = f2bf(v1.y);
    tv.u[6] = f2bf(v1.z); tv.u[7] = f2bf(v1.w);
    ((uint4*)xb)[i] = tv.v;
  }
}

// ---------------- CSR build, phase B ----------------
__global__ __launch_bounds__(256) void bucket_fill2(
    const int2* __restrict__ stage, const int* __restrict__ btot,
    int* __restrict__ offs, int* __restrict__ cnt, float* __restrict__ inv,
    int* __restrict__ csr, int N) {
  __shared__ int lhist[256];
  __shared__ int lscan[256];
  __shared__ int lcur[256];
  __shared__ int red[256];
  const int b = blockIdx.x;
  const int t = threadIdx.x;
  int sum = 0;
  for (int j = t; j < b; j += 256) sum += btot[j];
  red[t] = sum;
  lhist[t] = 0;
  __syncthreads();
  for (int d = 128; d; d >>= 1) {
    if (t < d) red[t] += red[t + d];
    __syncthreads();
  }
  const int base = red[0];
  const int count = btot[b];
  const int2* sp = stage + (size_t)b * CAP;
  for (int i = t; i < count; i += 256)
    atomicAdd(&lhist[sp[i].y & 255], 1);
  __syncthreads();
  int v = lhist[t];
  lscan[t] = v;
  __syncthreads();
  for (int d = 1; d < 256; d <<= 1) {
    int tv = (t >= d) ? lscan[t - d] : 0;
    __syncthreads();
    lscan[t] += tv;
    __syncthreads();
  }
  const int excl = lscan[t] - v;
  const int node = b * 256 + t;
  if (node < N) {
    offs[node] = base + excl;
    cnt[node] = v;
    inv[node] = 1.0f / (float)((v > 1) ? v : 1);
  }
  lcur[t] = base + excl;
  __syncthreads();
  for (int i = t; i < count; i += 256) {
    int2 sd = sp[i];
    int p = atomicAdd(&lcur[sd.y & 255], 1);
    csr[p] = sd.x;
  }
}

// ---------------- fused aggregate + dual GEMM ----------------
// out = mean_agg(A)@Wl^T + A@Wr^T + b (+relu), A bf16 [n,128].
// Each wave owns 16 rows; the aggregate is accumulated DIRECTLY into MFMA
// A-fragment slices (lane (nn,quad) gathers its 4x16B column slices of each
// neighbor row) — the M intermediate never touches memory.
// LDS holds ONE 32 KiB W matrix at a time (Wl phase, then restage Wr) to keep
// 5 blocks/CU for gather latency hiding.
template <int RELU, int OUTBF>
__global__ __launch_bounds__(256, 4) void agg_gemm(
    const unsigned short* __restrict__ A,   // node features bf16 [n,128]
    const unsigned short* __restrict__ Wp,  // Wl frag-order at +0, Wr at +16384
    const float* __restrict__ bias, const float* __restrict__ inv,
    const int* __restrict__ offs, const int* __restrict__ cnt,
    const int* __restrict__ csr, void* __restrict__ outp, int n) {
  __shared__ unsigned short wsh[16384];  // 32 KiB: one W matrix
  const int tid = threadIdx.x;

  // stage Wl
  {
    const uint4* wsrc = (const uint4*)Wp;
    uint4* wdst = (uint4*)wsh;
#pragma unroll
    for (int it = 0; it < 8; ++it) wdst[it * 256 + tid] = wsrc[it * 256 + tid];
  }

  const int lane = tid & 63;
  const int wave = tid >> 6;
  const int nn = lane & 15;
  const int quad = lane >> 4;
  const int rowbase = blockIdx.x * 64 + wave * 16;

  int nodeA = rowbase + nn;
  if (nodeA > n - 1) nodeA = n - 1;

  // self row fragments (in flight during gather)
  short8 asf[4];
#pragma unroll
  for (int s = 0; s < 4; ++s)
    asf[s] = *(const short8*)(A + (size_t)nodeA * 128 + s * 32 + quad * 8);

  const int deg = cnt[nodeA];
  const int off0 = offs[nodeA];
  const float sc = inv[nodeA];

  // wave max degree (deg identical across quads; reduce over nn bits)
  int md = deg;
  md = max(md, __shfl_xor(md, 1));
  md = max(md, __shfl_xor(md, 2));
  md = max(md, __shfl_xor(md, 4));
  md = max(md, __shfl_xor(md, 8));

  // gather-accumulate the mean directly into fragment slices
  f32x2 acc[4][4];
#pragma unroll
  for (int s = 0; s < 4; ++s)
#pragma unroll
    for (int p = 0; p < 4; ++p) acc[s][p] = (f32x2){0.f, 0.f};

  const char* Abase = (const char*)A;
  const int qoff = quad * 16;   // byte offset of this lane's 16B slice within 64B s-chunk

  int i0 = (0 < deg) ? csr[off0] : 0;
  int i1 = (1 < deg) ? csr[off0 + 1] : 0;
  for (int j = 0; j < md; j += 2) {
    int ni0 = (j + 2 < deg) ? csr[off0 + j + 2] : 0;
    int ni1 = (j + 3 < deg) ? csr[off0 + j + 3] : 0;
    const char* p0 = Abase + ((size_t)(unsigned)i0 << 8) + qoff;
    const char* p1 = Abase + ((size_t)(unsigned)i1 << 8) + qoff;
    uint4 v0[4], v1[4];
#pragma unroll
    for (int s = 0; s < 4; ++s) v0[s] = *(const uint4*)(p0 + s * 64);
#pragma unroll
    for (int s = 0; s < 4; ++s) v1[s] = *(const uint4*)(p1 + s * 64);
    if (j < deg) {
#pragma unroll
      for (int s = 0; s < 4; ++s) addf2(acc[s], v0[s]);
    }
    if (j + 1 < deg) {
#pragma unroll
      for (int s = 0; s < 4; ++s) addf2(acc[s], v1[s]);
    }
    i0 = ni0; i1 = ni1;
  }

  // mean scale + pack to bf16 A-fragments
  short8 am[4];
#pragma unroll
  for (int s = 0; s < 4; ++s) {
    union { unsigned short u[8]; short8 v; } t;
#pragma unroll
    for (int p = 0; p < 4; ++p) {
      t.u[2 * p] = f2bf(acc[s][p].x * sc);
      t.u[2 * p + 1] = f2bf(acc[s][p].y * sc);
    }
    am[s] = t.v;
  }

  f32x4 accc[8];
#pragma unroll
  for (int jt = 0; jt < 8; ++jt) accc[jt] = (f32x4){0.f, 0.f, 0.f, 0.f};

  __syncthreads();   // Wl staged (and everyone past the copy)

  // aggregate part: accc += am @ Wl^T
#pragma unroll
  for (int jt = 0; jt < 8; ++jt) {
#pragma unroll
    for (int s = 0; s < 4; ++s) {
      int c = (s * 8 + jt) * 4 + quad;
      short8 bl = *(const short8*)(wsh + (c * 16 + nn) * 8);
      accc[jt] = __builtin_amdgcn_mfma_f32_16x16x32_bf16(am[s], bl, accc[jt], 0, 0, 0);
    }
  }

  __syncthreads();   // all waves done reading Wl

  // restage Wr over the same buffer
  {
    const uint4* wsrc = (const uint4*)(Wp + 16384);
    uint4* wdst = (uint4*)wsh;
#pragma unroll
    for (int it = 0; it < 8; ++it) wdst[it * 256 + tid] = wsrc[it * 256 + tid];
  }
  __syncthreads();

  // self part: accc += asf @ Wr^T
#pragma unroll
  for (int jt = 0; jt < 8; ++jt) {
#pragma unroll
    for (int s = 0; s < 4; ++s) {
      int c = (s * 8 + jt) * 4 + quad;
      short8 br = *(const short8*)(wsh + (c * 16 + nn) * 8);
      accc[jt] = __builtin_amdgcn_mfma_f32_16x16x32_bf16(asf[s], br, accc[jt], 0, 0, 0);
    }
  }

  // epilogue
#pragma unroll
  for (int jt = 0; jt < 8; ++jt) {
    int col = jt * 16 + nn;
    float bv = bias[col];
#pragma unroll
    for (int r = 0; r < 4; ++r) {
      int ro = rowbase + quad * 4 + r;
      if (ro < n) {
        float o = accc[jt][r] + bv;
        if (RELU) o = fmaxf(o, 0.f);
        if (OUTBF) {
          ((unsigned short*)outp)[(size_t)ro * 128 + col] = f2bf(o);
        } else {
          ((float*)outp)[(size_t)ro * 128 + col] = o;
        }
      }
    }
  }
}

// ---------------- launch ----------------
// Aggregate-first + fully fused per layer:
//   out = mean_agg(A)@Wl^T + A@Wr^T + b   (agg accumulates straight into
// MFMA A-fragments — no M intermediate, 2 dispatches/layer -> 1).
// Buffers: xb (bf16 x) lives in d_out (dead before final agg_gemm writes it);
//          stage/hb share a ws region as before.

extern "C" void kernel_launch(void* const* d_in, const int* in_sizes, int n_in,
                              void* d_out, int out_size, void* d_ws, size_t ws_size,
                              hipStream_t stream) {
  const float* x = (const float*)d_in[0];
  const int* ei = (const int*)d_in[1];
  const float* W1l = (const float*)d_in[2];
  const float* b1 = (const float*)d_in[3];
  const float* W1r = (const float*)d_in[4];
  const float* W2l = (const float*)d_in[5];
  const float* b2 = (const float*)d_in[6];
  const float* W2r = (const float*)d_in[7];
  float* out = (float*)d_out;

  const int N = in_sizes[0] / 128;
  const int E = in_sizes[1] / 2;
  const int nb = (N + 255) / 256;   // buckets of 256 nodes; must be <= NBMAX

  char* p = (char*)d_ws;
  auto alloc = [&](size_t bytes) {
    char* r = p;
    p += (bytes + 255) & ~(size_t)255;
    return r;
  };
  int* btot = (int*)alloc((size_t)NBMAX * 4);
  int* cnt = (int*)alloc((size_t)N * 4);
  int* offs = (int*)alloc((size_t)N * 4);
  float* inv = (float*)alloc((size_t)N * 4);
  int* csr = (int*)alloc((size_t)E * 4);
  unsigned short* Wpb = (unsigned short*)alloc((size_t)4 * 16384 * 2); // 128 KB
  size_t stage_bytes = (size_t)nb * CAP * 8;
  size_t hb_bytes = (size_t)N * 128 * 2;
  char* shared_region = alloc(stage_bytes > hb_bytes ? stage_bytes : hb_bytes);
  unsigned short* hb = (unsigned short*)shared_region;  // h (bf16) after CSR done
  int2* stage = (int2*)shared_region;                   // staging during CSR build

  // xb: bf16 cast of x, parked in d_out (only the last agg_gemm writes d_out)
  unsigned short* xb = (unsigned short*)d_out;

  hipMemsetAsync(btot, 0, (size_t)nb * 4, stream);

  const int SB = (E + 4095) / 4096;
  prep<<<SB + 4 + 2048, 256, 0, stream>>>(ei, E, btot, stage, SB,
                                          x, xb, N * 128 / 8,
                                          W1l, W1r, W2l, W2r, Wpb);
  bucket_fill2<<<nb, 256, 0, stream>>>(stage, btot, offs, cnt, inv, csr, N);

  const int gb = (N + 63) / 64;

  // layer 1: h = relu(mean_agg(xb)@W1l^T + xb@W1r^T + b1) -> hb (bf16)
  agg_gemm<1, 1><<<gb, 256, 0, stream>>>(xb, Wpb, b1, inv, offs, cnt, csr,
                                         (void*)hb, N);
  // layer 2: out = mean_agg(hb)@W2l^T + hb@W2r^T + b2 -> d_out (f32)
  agg_gemm<0, 0><<<gb, 256, 0, stream>>>(hb, Wpb + 32768, b2, inv, offs, cnt, csr,
                                         (void*)out, N);
}